// Round 2
// baseline (1180.105 us; speedup 1.0000x reference)
//
#include <hip/hip_runtime.h>

// CRF forward: out[b] = gold_score(b) - log_partition(b)
// B=256 blocks, one per sequence; 256 threads: thread (j = tid>>1, h = tid&1)
// owns output state j and sums half of the 128-wide "from" dimension.
// E[j][i] = exp(trans[j][i]) lives in registers as f16 (32 VGPRs/thread);
// per step the shared activation a[i] = exp(alpha[i]-m) (f16, 256B LDS) is
// read with ds_read_b128 and combined with v_dot2_f32_f16 (fp32 accum).

typedef _Float16 half_t;
typedef _Float16 h2 __attribute__((ext_vector_type(2)));
typedef _Float16 h8 __attribute__((ext_vector_type(8)));

#define TB  1024
#define NUM 126
#define LBL 128

__device__ __forceinline__ float dot2(h2 a, h2 b, float c) {
#if __has_builtin(__builtin_amdgcn_fdot2)
  return __builtin_amdgcn_fdot2(a, b, c, false);
#else
  return c + (float)a[0] * (float)b[0] + (float)a[1] * (float)b[1];
#endif
}

__global__ __launch_bounds__(256, 1)
void crf_fwd(const float* __restrict__ logits, const int* __restrict__ labels,
             const int* __restrict__ lens, const float* __restrict__ trans,
             float* __restrict__ out)
{
  const int b   = blockIdx.x;
  const int tid = threadIdx.x;
  const int j   = tid >> 1;   // output state 0..127
  const int h   = tid & 1;    // which 64-wide half of the sum
  const int len = lens[b];

  __shared__ h8    a_sh8[16];          // 128 f16 activations
  __shared__ float red[8];
  __shared__ float gold_sh;
  half_t* a_sh = (half_t*)a_sh8;

  const float* lgbase = logits + (size_t)b * TB * NUM;
  const int*   lab    = labels + (size_t)b * TB;

  // ---- E fragment into registers: E[j][64h + k], k=0..63 (f16)
  h8 E8[8];
  {
    const float* tr = trans + j * LBL + 64 * h;
    #pragma unroll
    for (int q = 0; q < 8; ++q) {
      h8 v;
      #pragma unroll
      for (int e = 0; e < 8; ++e) v[e] = (half_t)__expf(tr[q * 8 + e]);
      E8[q] = v;
    }
  }

  // ---- gold score (unary + binary transitions along the label path)
  float g = 0.f;
  #pragma unroll
  for (int kk = 0; kk < 4; ++kk) {
    int t = tid + 256 * kk;
    if (t < len) {
      int lt = lab[t];
      int lp = (t == 0) ? (LBL - 2) : lab[t - 1];   // start state = 126
      g += lgbase[(size_t)t * NUM + lt] + trans[lt * LBL + lp];
    }
  }
  if (tid == 0) g += trans[(LBL - 1) * LBL + lab[len - 1]];  // -> end state
  #pragma unroll
  for (int o = 1; o < 64; o <<= 1) g += __shfl_xor(g, o);
  if ((tid & 63) == 0) red[4 + (tid >> 6)] = g;

  // ---- alpha_0: start=0, others -100  =>  a = exp(alpha-0)
  if (tid < 128) a_sh[tid] = (half_t)((tid == LBL - 2) ? 1.0f : 0.0f);
  __syncthreads();
  if (tid == 0) gold_sh = red[4] + red[5] + red[6] + red[7];

  float sigma = 0.0f;   // current normalizer (exact max of alpha)
  float alpha = 0.0f;   // this thread's alpha[j] (true, unnormalized)

  // ---- logit software pipeline, depth 4
  float lbuf[4];
  #pragma unroll
  for (int d = 0; d < 4; ++d)
    lbuf[d] = (j < NUM && d < len) ? lgbase[(size_t)d * NUM + j] : -1000.0f;

  for (int t = 0; t < len; ++t) {
    // GEMV half-row: s_j^h = sum_{k} E[j][64h+k] * a[64h+k]
    float s0 = 0.f, s1 = 0.f, s2 = 0.f, s3 = 0.f;
    const h8* ap = (const h8*)(a_sh + 64 * h);
    #pragma unroll
    for (int q = 0; q < 8; ++q) {
      h8 av = ap[q], ev = E8[q];
      s0 = dot2(__builtin_shufflevector(av, av, 0, 1),
                __builtin_shufflevector(ev, ev, 0, 1), s0);
      s1 = dot2(__builtin_shufflevector(av, av, 2, 3),
                __builtin_shufflevector(ev, ev, 2, 3), s1);
      s2 = dot2(__builtin_shufflevector(av, av, 4, 5),
                __builtin_shufflevector(ev, ev, 4, 5), s2);
      s3 = dot2(__builtin_shufflevector(av, av, 6, 7),
                __builtin_shufflevector(ev, ev, 6, 7), s3);
    }
    float s = (s0 + s1) + (s2 + s3);
    s += __shfl_xor(s, 1);            // pair combine: both lanes get full sum
    s = fmaxf(s, 1e-30f);             // row j=126 is all-zero -> keep finite

    float lg = lbuf[t & 3];
    int tn = t + 4;                    // prefetch logits for t+4
    if (tn < len && j < NUM) lbuf[t & 3] = lgbase[(size_t)tn * NUM + j];

    alpha = lg + sigma + __logf(s);

    // exact max over 128 states (pairs hold duplicates -> skip xor 1)
    float wm = alpha;
    #pragma unroll
    for (int o = 2; o < 64; o <<= 1) wm = fmaxf(wm, __shfl_xor(wm, o));
    if ((tid & 63) == 0) red[tid >> 6] = wm;
    __syncthreads();
    float m = fmaxf(fmaxf(red[0], red[1]), fmaxf(red[2], red[3]));
    float av = __expf(alpha - m);
    if (h == 0) a_sh[j] = (half_t)av;
    sigma = m;
    __syncthreads();
  }

  // ---- norm = logsumexp_j(alpha[j] + trans[end][j]); out = gold - norm
  float v = alpha + trans[(LBL - 1) * LBL + j];
  float wm = v;
  #pragma unroll
  for (int o = 2; o < 64; o <<= 1) wm = fmaxf(wm, __shfl_xor(wm, o));
  if ((tid & 63) == 0) red[tid >> 6] = wm;
  __syncthreads();
  float M = fmaxf(fmaxf(red[0], red[1]), fmaxf(red[2], red[3]));
  float p = (h == 0) ? __expf(v - M) : 0.0f;
  #pragma unroll
  for (int o = 1; o < 64; o <<= 1) p += __shfl_xor(p, o);
  if ((tid & 63) == 0) red[4 + (tid >> 6)] = p;
  __syncthreads();
  if (tid == 0) {
    float S = red[4] + red[5] + red[6] + red[7];
    out[b] = gold_sh - (M + __logf(S));
  }
}

extern "C" void kernel_launch(void* const* d_in, const int* in_sizes, int n_in,
                              void* d_out, int out_size, void* d_ws, size_t ws_size,
                              hipStream_t stream) {
  const float* logits = (const float*)d_in[0];
  const int*   labels = (const int*)d_in[1];
  const int*   lens   = (const int*)d_in[2];
  const float* trans  = (const float*)d_in[3];
  float* out = (float*)d_out;
  (void)in_sizes; (void)n_in; (void)out_size; (void)d_ws; (void)ws_size;
  crf_fwd<<<256, 256, 0, stream>>>(logits, labels, lens, trans, out);
}

// Round 5
// 1117.786 us; speedup vs baseline: 1.0558x; 1.0558x over previous
//
#include <hip/hip_runtime.h>

// CRF forward, latency-optimized: ONE WAVE per sequence (no __syncthreads in
// the time loop). 256 blocks x 64 threads. Lane l owns states j0=l, j1=l+64.
// E = exp(trans) lives in 128 VGPRs as f16 (two full rows per lane).
// Per step: 16 broadcast ds_read_b128 of the 256B activation vector,
// 128 v_dot2_f32_f16 per lane, in-wave DPP max (no ds_swizzle), exp, one
// packed ds_write_b32, s_waitcnt lgkmcnt(0) (__threadfence_block).

typedef _Float16 half_t;
typedef _Float16 h2 __attribute__((ext_vector_type(2)));
typedef _Float16 h8 __attribute__((ext_vector_type(8)));

#define TB  1024
#define NUM 126
#define LBL 128

__device__ __forceinline__ float dot2(h2 a, h2 b, float c) {
  return __builtin_amdgcn_fdot2(a, b, c, false);
}

template <int U>
__device__ __forceinline__ float dotu(h8 a, h8 e, float c) {
  return dot2(__builtin_shufflevector(a, a, 2 * U, 2 * U + 1),
              __builtin_shufflevector(e, e, 2 * U, 2 * U + 1), c);
}

template <int CTRL>
__device__ __forceinline__ float dpp_max_step(float x) {
  int xi = __float_as_int(x);
  int yi = __builtin_amdgcn_update_dpp(xi, xi, CTRL, 0xF, 0xF, false);
  return fmaxf(x, __int_as_float(yi));
}

// max over all 64 lanes, result broadcast to all lanes via readlane(63)
__device__ __forceinline__ float wave_max64(float x) {
  x = dpp_max_step<0x111>(x);  // row_shr:1
  x = dpp_max_step<0x112>(x);  // row_shr:2
  x = dpp_max_step<0x114>(x);  // row_shr:4
  x = dpp_max_step<0x118>(x);  // row_shr:8
  x = dpp_max_step<0x142>(x);  // row_bcast:15
  x = dpp_max_step<0x143>(x);  // row_bcast:31
  return __int_as_float(__builtin_amdgcn_readlane(__float_as_int(x), 63));
}

__global__ __launch_bounds__(64, 1)
void crf_fwd(const float* __restrict__ logits, const int* __restrict__ labels,
             const int* __restrict__ lens, const float* __restrict__ trans,
             float* __restrict__ out)
{
  const int b  = blockIdx.x;
  const int l  = threadIdx.x;      // lane 0..63
  const int j0 = l;                // state j0 (always < 126: real logits)
  const int j1 = l + 64;           // state j1 (126,127 for lanes 62,63)
  const int len = lens[b];

  __shared__ h2 a_sh[64];          // a packed: dword l = (a[l], a[l+64])
  h8* a_sh8 = (h8*)a_sh;

  const float* lgbase = logits + (size_t)b * TB * NUM;
  const int*   lab    = labels + (size_t)b * TB;

  // ---- E rows (f16) in registers, permuted to match a_sh interleaved order:
  // linear f16 position p in a_sh corresponds to state i(p) = (p>>1) + 64*(p&1)
  h8 E0[16], E1[16];
  {
    const float* tr0 = trans + j0 * LBL;
    const float* tr1 = trans + j1 * LBL;
    #pragma unroll
    for (int q = 0; q < 16; ++q) {
      h8 v0, v1;
      #pragma unroll
      for (int e = 0; e < 8; ++e) {
        int p = 8 * q + e;
        int i = (p >> 1) + 64 * (p & 1);
        v0[e] = (half_t)__expf(tr0[i]);
        v1[e] = (half_t)__expf(tr1[i]);
      }
      E0[q] = v0; E1[q] = v1;
    }
  }

  // ---- gold score (one-time; shuffles here are off the critical loop)
  float g = 0.f;
  #pragma unroll
  for (int kk = 0; kk < 16; ++kk) {
    int t = l + 64 * kk;
    if (t < len) {
      int lt = lab[t];
      int lp = (t == 0) ? (LBL - 2) : lab[t - 1];   // start state = 126
      g += lgbase[(size_t)t * NUM + lt] + trans[lt * LBL + lp];
    }
  }
  if (l == 0) g += trans[(LBL - 1) * LBL + lab[len - 1]];  // -> end state
  #pragma unroll
  for (int o = 1; o < 64; o <<= 1) g += __shfl_xor(g, o);
  const float gold = g;

  // ---- alpha_0: start(126)=0, others -100. a = exp(alpha - 0)
  float alpha0 = -100.0f;                    // j0 in 0..63, never start
  float alpha1 = (j1 == LBL - 2) ? 0.0f : -100.0f;
  {
    h2 a_init;
    a_init[0] = (half_t)0.0f;
    a_init[1] = (half_t)((j1 == LBL - 2) ? 1.0f : 0.0f);
    a_sh[l] = a_init;
  }
  __threadfence_block();                     // s_waitcnt lgkmcnt(0)

  float sigma = 0.0f;

  // ---- logit prefetch ring, depth 4
  float lbuf0[4], lbuf1[4];
  #pragma unroll
  for (int d = 0; d < 4; ++d) {
    lbuf0[d] = (d < len) ? lgbase[(size_t)d * NUM + j0] : -1000.0f;
    lbuf1[d] = (d < len && j1 < NUM) ? lgbase[(size_t)d * NUM + j1] : -1000.0f;
  }

  for (int t = 0; t < len; ++t) {
    // s_{j} = sum_i E[j][i] * a[i], both rows, fp32 accum, 2 accums per row
    float s0a = 0.f, s0b = 0.f, s1a = 0.f, s1b = 0.f;
    #pragma unroll
    for (int q = 0; q < 16; q += 2) {
      h8 avA = a_sh8[q], avB = a_sh8[q + 1];   // uniform addr -> broadcast
      h8 e0A = E0[q], e0B = E0[q + 1], e1A = E1[q], e1B = E1[q + 1];
      s0a = dotu<0>(avA, e0A, s0a);  s0b = dotu<0>(avB, e0B, s0b);
      s1a = dotu<0>(avA, e1A, s1a);  s1b = dotu<0>(avB, e1B, s1b);
      s0a = dotu<1>(avA, e0A, s0a);  s0b = dotu<1>(avB, e0B, s0b);
      s1a = dotu<1>(avA, e1A, s1a);  s1b = dotu<1>(avB, e1B, s1b);
      s0a = dotu<2>(avA, e0A, s0a);  s0b = dotu<2>(avB, e0B, s0b);
      s1a = dotu<2>(avA, e1A, s1a);  s1b = dotu<2>(avB, e1B, s1b);
      s0a = dotu<3>(avA, e0A, s0a);  s0b = dotu<3>(avB, e0B, s0b);
      s1a = dotu<3>(avA, e1A, s1a);  s1b = dotu<3>(avB, e1B, s1b);
    }
    float s0 = fmaxf(s0a + s0b, 1e-30f);
    float s1 = fmaxf(s1a + s1b, 1e-30f);

    float lg0 = lbuf0[t & 3], lg1 = lbuf1[t & 3];
    int tn = t + 4;                            // prefetch logits for t+4
    if (tn < len) {
      lbuf0[t & 3] = lgbase[(size_t)tn * NUM + j0];
      if (j1 < NUM) lbuf1[t & 3] = lgbase[(size_t)tn * NUM + j1];
    }

    alpha0 = lg0 + sigma + __logf(s0);
    alpha1 = lg1 + sigma + __logf(s1);

    // exact max over 128 states, all in-wave (DPP, no LDS, no barrier)
    float m = wave_max64(fmaxf(alpha0, alpha1));

    float a0 = __expf(alpha0 - m);
    float a1 = __expf(alpha1 - m);
    h2 pk;
    pk[0] = (half_t)a0;                        // v_cvt_pkrtz via codegen
    pk[1] = (half_t)a1;
    a_sh[l] = pk;                              // one ds_write_b32
    __threadfence_block();                     // order write before reads
    sigma = m;
  }

  // ---- norm = logsumexp_j(alpha[j] + trans[end][j]); out = gold - norm
  float v0 = alpha0 + trans[(LBL - 1) * LBL + j0];
  float v1 = alpha1 + trans[(LBL - 1) * LBL + j1];
  float M = wave_max64(fmaxf(v0, v1));
  float p = __expf(v0 - M) + __expf(v1 - M);
  #pragma unroll
  for (int o = 1; o < 64; o <<= 1) p += __shfl_xor(p, o);
  if (l == 0) out[b] = gold - (M + __logf(p));
}

extern "C" void kernel_launch(void* const* d_in, const int* in_sizes, int n_in,
                              void* d_out, int out_size, void* d_ws, size_t ws_size,
                              hipStream_t stream) {
  const float* logits = (const float*)d_in[0];
  const int*   labels = (const int*)d_in[1];
  const int*   lens   = (const int*)d_in[2];
  const float* trans  = (const float*)d_in[3];
  float* out = (float*)d_out;
  (void)in_sizes; (void)n_in; (void)out_size; (void)d_ws; (void)ws_size;
  crf_fwd<<<256, 64, 0, stream>>>(logits, labels, lens, trans, out);
}

// Round 6
// 671.645 us; speedup vs baseline: 1.7570x; 1.6642x over previous
//
#include <hip/hip_runtime.h>

// CRF forward, latency-optimized: ONE WAVE per sequence, no barriers, no
// fences in the time loop. 256 blocks x 64 threads; lane l owns states
// j0=l, j1=l+64. E=exp(trans) in 128 VGPRs (f16). Recurrence kept in the
// MULTIPLICATIVE domain: w = (E·a)*eL, a_next = w/max(w); log/exp moved off
// the critical chain (eL=exp(logit) from prefetch; Sigma += log(m) on a side
// chain). Time loop unrolled x4 with constant-index prefetch slots so logit
// loads stay in flight across 4 iterations (fine-grained vmcnt, never
// drained: NO __threadfence_block — it would emit s_waitcnt vmcnt(0)).

typedef _Float16 half_t;
typedef _Float16 h2 __attribute__((ext_vector_type(2)));
typedef _Float16 h8 __attribute__((ext_vector_type(8)));

#define TB  1024
#define NUM 126
#define LBL 128

__device__ __forceinline__ float dot2(h2 a, h2 b, float c) {
  return __builtin_amdgcn_fdot2(a, b, c, false);
}

template <int U>
__device__ __forceinline__ float dotu(h8 a, h8 e, float c) {
  return dot2(__builtin_shufflevector(a, a, 2 * U, 2 * U + 1),
              __builtin_shufflevector(e, e, 2 * U, 2 * U + 1), c);
}

template <int CTRL>
__device__ __forceinline__ float dpp_max_step(float x) {
  int xi = __float_as_int(x);
  int yi = __builtin_amdgcn_update_dpp(xi, xi, CTRL, 0xF, 0xF, false);
  return fmaxf(x, __int_as_float(yi));
}

// max over all 64 lanes, broadcast to all lanes
__device__ __forceinline__ float wave_max64(float x) {
  x = dpp_max_step<0x111>(x);  // row_shr:1
  x = dpp_max_step<0x112>(x);  // row_shr:2
  x = dpp_max_step<0x114>(x);  // row_shr:4
  x = dpp_max_step<0x118>(x);  // row_shr:8
  x = dpp_max_step<0x142>(x);  // row_bcast:15
  x = dpp_max_step<0x143>(x);  // row_bcast:31
  return __int_as_float(__builtin_amdgcn_readlane(__float_as_int(x), 63));
}

// lgkmcnt(0) ONLY: vmcnt=63, expcnt=7 -> never waits on global loads
#define LGKM_WAIT() __builtin_amdgcn_s_waitcnt(0xC07F)

__global__ __launch_bounds__(64, 1)
void crf_fwd(const float* __restrict__ logits, const int* __restrict__ labels,
             const int* __restrict__ lens, const float* __restrict__ trans,
             float* __restrict__ out)
{
  const int b  = blockIdx.x;
  const int l  = threadIdx.x;      // lane 0..63
  const int j0 = l;                // state j0 (< 126: always a real label)
  const int j1 = l + 64;           // state j1 (126,127 on lanes 62,63)
  const int len = lens[b];

  __shared__ h2 a_sh[64];          // dword l = (a[l], a[l+64]), f16
  h8* a_sh8 = (h8*)a_sh;

  const float* lgbase = logits + (size_t)b * TB * NUM;
  const int*   lab    = labels + (size_t)b * TB;

  // ---- E rows (f16) in registers, permuted to the a_sh interleaved order:
  // f16 position p in a_sh holds state i(p) = (p>>1) + 64*(p&1)
  h8 E0[16], E1[16];
  {
    const float* tr0 = trans + j0 * LBL;
    const float* tr1 = trans + j1 * LBL;
    #pragma unroll
    for (int q = 0; q < 16; ++q) {
      h8 v0, v1;
      #pragma unroll
      for (int e = 0; e < 8; ++e) {
        int p = 8 * q + e;
        int i = (p >> 1) + 64 * (p & 1);
        v0[e] = (half_t)__expf(tr0[i]);
        v1[e] = (half_t)__expf(tr1[i]);
      }
      E0[q] = v0; E1[q] = v1;
    }
  }

  // ---- gold score (one-time, off the recurrence)
  float g = 0.f;
  #pragma unroll
  for (int kk = 0; kk < 16; ++kk) {
    int t = l + 64 * kk;
    if (t < len) {
      int lt = lab[t];
      int lp = (t == 0) ? (LBL - 2) : lab[t - 1];   // start state = 126
      g += lgbase[(size_t)t * NUM + lt] + trans[lt * LBL + lp];
    }
  }
  if (l == 0) g += trans[(LBL - 1) * LBL + lab[len - 1]];  // -> end
  #pragma unroll
  for (int o = 1; o < 64; o <<= 1) g += __shfl_xor(g, o);
  const float gold = g;

  // ---- a_0 = one-hot(start=126); same-wave in-order DS, no fence needed
  {
    h2 a_init;
    a_init[0] = (half_t)0.0f;
    a_init[1] = (half_t)((j1 == LBL - 2) ? 1.0f : 0.0f);
    a_sh[l] = a_init;
    LGKM_WAIT();
  }

  // ---- logit prefetch, 4 constant-index register slots
  float plg0[4], plg1[4];
  #pragma unroll
  for (int d = 0; d < 4; ++d) {
    plg0[d] = (d < len) ? lgbase[(size_t)d * NUM + j0] : -1000.0f;
    plg1[d] = (d < len && j1 < NUM) ? lgbase[(size_t)d * NUM + j1] : -1000.0f;
  }

  float Sigma  = 0.f;                 // sum of log(m_t)  (side chain)
  float w0_out = 1.f, w1_out = 1.f, m_out = 1.f;

#define STEP(K, PF)                                                         \
  {                                                                         \
    float eL0 = __expf(plg0[K]);   /* off-chain: from prefetch */           \
    float eL1 = __expf(plg1[K]);                                            \
    float s0a = 0.f, s0b = 0.f, s1a = 0.f, s1b = 0.f;                       \
    _Pragma("unroll")                                                       \
    for (int q = 0; q < 16; q += 2) {                                       \
      h8 avA = a_sh8[q], avB = a_sh8[q + 1];  /* uniform addr broadcast */  \
      h8 e0A = E0[q], e0B = E0[q + 1], e1A = E1[q], e1B = E1[q + 1];        \
      s0a = dotu<0>(avA, e0A, s0a);  s0b = dotu<0>(avB, e0B, s0b);          \
      s1a = dotu<0>(avA, e1A, s1a);  s1b = dotu<0>(avB, e1B, s1b);          \
      s0a = dotu<1>(avA, e0A, s0a);  s0b = dotu<1>(avB, e0B, s0b);          \
      s1a = dotu<1>(avA, e1A, s1a);  s1b = dotu<1>(avB, e1B, s1b);          \
      s0a = dotu<2>(avA, e0A, s0a);  s0b = dotu<2>(avB, e0B, s0b);          \
      s1a = dotu<2>(avA, e1A, s1a);  s1b = dotu<2>(avB, e1B, s1b);          \
      s0a = dotu<3>(avA, e0A, s0a);  s0b = dotu<3>(avB, e0B, s0b);          \
      s1a = dotu<3>(avA, e1A, s1a);  s1b = dotu<3>(avB, e1B, s1b);          \
    }                                                                       \
    float w0 = (s0a + s0b) * eL0;                                           \
    float w1 = (s1a + s1b) * eL1;                                           \
    float m  = wave_max64(fmaxf(w0, w1));                                   \
    float rv = __builtin_amdgcn_rcpf(m);                                    \
    h2 pk;                                                                  \
    pk[0] = (half_t)(w0 * rv);                                              \
    pk[1] = (half_t)(w1 * rv);                                              \
    a_sh[l] = pk;                                                           \
    LGKM_WAIT();            /* lgkm only; vmcnt stays outstanding */        \
    Sigma += __logf(m);     /* side chain, nothing in-loop consumes it */   \
    w0_out = w0; w1_out = w1; m_out = m;                                    \
    if (PF) {                                                               \
      int tn = t + (K) + 4;                                                 \
      if (tn < len) {                                                       \
        plg0[K] = lgbase[(size_t)tn * NUM + j0];                            \
        if (j1 < NUM) plg1[K] = lgbase[(size_t)tn * NUM + j1];              \
      }                                                                     \
    }                                                                       \
  }

  int t = 0;
  for (; t + 4 <= len; t += 4) {
    STEP(0, true) STEP(1, true) STEP(2, true) STEP(3, true)
  }
  const int rem = len - t;
  if (rem > 0) STEP(0, false)
  if (rem > 1) STEP(1, false)
  if (rem > 2) STEP(2, false)
#undef STEP

  // ---- alpha_len[j] = Sigma_{len-1} + log(w_len[j]);  Sigma incl. last m
  float SigmaPrev = Sigma - __logf(m_out);
  float alpha0 = SigmaPrev + __logf(w0_out);   // -inf for dead states: ok
  float alpha1 = SigmaPrev + __logf(w1_out);

  float v0 = alpha0 + trans[(LBL - 1) * LBL + j0];
  float v1 = alpha1 + trans[(LBL - 1) * LBL + j1];
  float M = wave_max64(fmaxf(v0, v1));
  float p = __expf(v0 - M) + __expf(v1 - M);
  #pragma unroll
  for (int o = 1; o < 64; o <<= 1) p += __shfl_xor(p, o);
  if (l == 0) out[b] = gold - (M + __logf(p));
}

extern "C" void kernel_launch(void* const* d_in, const int* in_sizes, int n_in,
                              void* d_out, int out_size, void* d_ws, size_t ws_size,
                              hipStream_t stream) {
  const float* logits = (const float*)d_in[0];
  const int*   labels = (const int*)d_in[1];
  const int*   lens   = (const int*)d_in[2];
  const float* trans  = (const float*)d_in[3];
  float* out = (float*)d_out;
  (void)in_sizes; (void)n_in; (void)out_size; (void)d_ws; (void)ws_size;
  crf_fwd<<<256, 64, 0, stream>>>(logits, labels, lens, trans, out);
}

// Round 7
// 602.271 us; speedup vs baseline: 1.9594x; 1.1152x over previous
//
#include <hip/hip_runtime.h>

// CRF forward, latency-optimized: ONE WAVE per sequence, no barriers/fences.
// 256 blocks x 64 threads; lane l owns states j0=l, j1=l+64.
// E=exp(trans) in 128 VGPRs (f16). Multiplicative recurrence:
//   w = (E·a)*eL,  a_next = w * 2^-k  (k = exponent of max w, EXACT scaling),
//   Kint += k (SALU side chain; no log/rcp in the loop).
// Main loop guarantees t+8 <= len so ALL in-loop prefetch loads are
// unconditional -> compiler emits precise s_waitcnt vmcnt(6), loads stay in
// flight across 4 steps. Lanes with j1>=NUM load a clamped column and mask
// eL1 to zero instead (value-mask, not load-mask).

typedef _Float16 half_t;
typedef _Float16 h2 __attribute__((ext_vector_type(2)));
typedef _Float16 h8 __attribute__((ext_vector_type(8)));

#define TB  1024
#define NUM 126
#define LBL 128

__device__ __forceinline__ float dot2(h2 a, h2 b, float c) {
  return __builtin_amdgcn_fdot2(a, b, c, false);
}

template <int U>
__device__ __forceinline__ float dotu(h8 a, h8 e, float c) {
  return dot2(__builtin_shufflevector(a, a, 2 * U, 2 * U + 1),
              __builtin_shufflevector(e, e, 2 * U, 2 * U + 1), c);
}

template <int CTRL>
__device__ __forceinline__ float dpp_max_step(float x) {
  int xi = __float_as_int(x);
  int yi = __builtin_amdgcn_update_dpp(xi, xi, CTRL, 0xF, 0xF, false);
  return fmaxf(x, __int_as_float(yi));
}

// max over all 64 lanes, broadcast via readlane(63) (uniform/SGPR result)
__device__ __forceinline__ float wave_max64(float x) {
  x = dpp_max_step<0x111>(x);  // row_shr:1
  x = dpp_max_step<0x112>(x);  // row_shr:2
  x = dpp_max_step<0x114>(x);  // row_shr:4
  x = dpp_max_step<0x118>(x);  // row_shr:8
  x = dpp_max_step<0x142>(x);  // row_bcast:15
  x = dpp_max_step<0x143>(x);  // row_bcast:31
  return __int_as_float(__builtin_amdgcn_readlane(__float_as_int(x), 63));
}

// lgkmcnt(0) ONLY (vmcnt=63, expcnt=7): never waits on global loads
#define LGKM_WAIT() __builtin_amdgcn_s_waitcnt(0xC07F)

__global__ __launch_bounds__(64, 1)
void crf_fwd(const float* __restrict__ logits, const int* __restrict__ labels,
             const int* __restrict__ lens, const float* __restrict__ trans,
             float* __restrict__ out)
{
  const int b  = blockIdx.x;
  const int l  = threadIdx.x;      // lane 0..63
  const int j0 = l;                // state j0 (< 126: always a real label)
  const int j1 = l + 64;           // state j1 (126,127 on lanes 62,63)
  const int off1 = (j1 < NUM) ? j1 : (NUM - 1);  // clamped col (load safety)
  const float mask1 = (j1 < NUM) ? 1.0f : 0.0f;  // value mask for eL1
  const int len = lens[b];

  __shared__ h2 a_sh[64];          // dword l = (a[l], a[l+64]), f16
  h8* a_sh8 = (h8*)a_sh;

  const float* lgbase = logits + (size_t)b * TB * NUM;
  const int*   lab    = labels + (size_t)b * TB;

  // ---- E rows (f16) in registers, permuted to the a_sh interleaved order:
  // f16 position p in a_sh holds state i(p) = (p>>1) + 64*(p&1)
  h8 E0[16], E1[16];
  {
    const float* tr0 = trans + j0 * LBL;
    const float* tr1 = trans + j1 * LBL;
    #pragma unroll
    for (int q = 0; q < 16; ++q) {
      h8 v0, v1;
      #pragma unroll
      for (int e = 0; e < 8; ++e) {
        int p = 8 * q + e;
        int i = (p >> 1) + 64 * (p & 1);
        v0[e] = (half_t)__expf(tr0[i]);
        v1[e] = (half_t)__expf(tr1[i]);
      }
      E0[q] = v0; E1[q] = v1;
    }
  }

  // ---- gold score (one-time, off the recurrence)
  float g = 0.f;
  #pragma unroll
  for (int kk = 0; kk < 16; ++kk) {
    int t = l + 64 * kk;
    if (t < len) {
      int lt = lab[t];
      int lp = (t == 0) ? (LBL - 2) : lab[t - 1];   // start state = 126
      g += lgbase[(size_t)t * NUM + lt] + trans[lt * LBL + lp];
    }
  }
  if (l == 0) g += trans[(LBL - 1) * LBL + lab[len - 1]];  // -> end
  #pragma unroll
  for (int o = 1; o < 64; o <<= 1) g += __shfl_xor(g, o);
  const float gold = g;

  // ---- a_0 = one-hot(start=126); same-wave in-order DS
  {
    h2 a_init;
    a_init[0] = (half_t)0.0f;
    a_init[1] = (half_t)((j1 == LBL - 2) ? 1.0f : 0.0f);
    a_sh[l] = a_init;
    LGKM_WAIT();
  }

  // ---- logit prefetch: rows 0..3 unconditional (buffer is full TB rows)
  float plg0[4], plg1[4];
  #pragma unroll
  for (int d = 0; d < 4; ++d) {
    plg0[d] = lgbase[(size_t)d * NUM + j0];
    plg1[d] = lgbase[(size_t)d * NUM + off1];
  }

  int   Kint = 0;                   // sum of per-step exponents (side chain)
  int   klast = 0;
  float w0_out = 1.f, w1_out = 1.f;

#define STEP_BODY(Q0, Q1)                                                   \
  {                                                                         \
    float eL0 = __expf(Q0);                                                 \
    float eL1 = __expf(Q1) * mask1;                                         \
    float s0a = 0.f, s0b = 0.f, s1a = 0.f, s1b = 0.f;                       \
    _Pragma("unroll")                                                       \
    for (int q = 0; q < 16; q += 2) {                                       \
      h8 avA = a_sh8[q], avB = a_sh8[q + 1];  /* uniform addr broadcast */  \
      h8 e0A = E0[q], e0B = E0[q + 1], e1A = E1[q], e1B = E1[q + 1];        \
      s0a = dotu<0>(avA, e0A, s0a);  s0b = dotu<0>(avB, e0B, s0b);          \
      s1a = dotu<0>(avA, e1A, s1a);  s1b = dotu<0>(avB, e1B, s1b);          \
      s0a = dotu<1>(avA, e0A, s0a);  s0b = dotu<1>(avB, e0B, s0b);          \
      s1a = dotu<1>(avA, e1A, s1a);  s1b = dotu<1>(avB, e1B, s1b);          \
      s0a = dotu<2>(avA, e0A, s0a);  s0b = dotu<2>(avB, e0B, s0b);          \
      s1a = dotu<2>(avA, e1A, s1a);  s1b = dotu<2>(avB, e1B, s1b);          \
      s0a = dotu<3>(avA, e0A, s0a);  s0b = dotu<3>(avB, e0B, s0b);          \
      s1a = dotu<3>(avA, e1A, s1a);  s1b = dotu<3>(avB, e1B, s1b);          \
    }                                                                       \
    float w0 = (s0a + s0b) * eL0;                                           \
    float w1 = (s1a + s1b) * eL1;                                           \
    float m  = wave_max64(fmaxf(w0, w1));      /* uniform (SGPR) */         \
    int   k  = (__float_as_int(m) >> 23) - 127;      /* m>0 normal */       \
    float sc = __int_as_float((127 - k) << 23);      /* 2^-k EXACT */       \
    h2 pk;                                                                  \
    pk[0] = (half_t)(w0 * sc);                                              \
    pk[1] = (half_t)(w1 * sc);                                              \
    a_sh[l] = pk;                                                           \
    LGKM_WAIT();              /* lgkm only; vmcnt stays outstanding */      \
    Kint += k;                /* SALU side chain */                         \
    klast = k; w0_out = w0; w1_out = w1;                                    \
  }

  int t = 0;
  // main loop: prefetched rows t+4..t+7 <= len-1, so loads UNCONDITIONAL
  for (; t + 8 <= len; t += 4) {
    const float* pnext = lgbase + (size_t)(t + 4) * NUM;
    STEP_BODY(plg0[0], plg1[0])
    plg0[0] = pnext[0 * NUM + j0];  plg1[0] = pnext[0 * NUM + off1];
    STEP_BODY(plg0[1], plg1[1])
    plg0[1] = pnext[1 * NUM + j0];  plg1[1] = pnext[1 * NUM + off1];
    STEP_BODY(plg0[2], plg1[2])
    plg0[2] = pnext[2 * NUM + j0];  plg1[2] = pnext[2 * NUM + off1];
    STEP_BODY(plg0[3], plg1[3])
    plg0[3] = pnext[3 * NUM + j0];  plg1[3] = pnext[3 * NUM + off1];
  }
  // remainder: first up to 4 steps from slots (constant indices only)
  const int rem = len - t;
  if (rem > 0) STEP_BODY(plg0[0], plg1[0])
  if (rem > 1) STEP_BODY(plg0[1], plg1[1])
  if (rem > 2) STEP_BODY(plg0[2], plg1[2])
  if (rem > 3) STEP_BODY(plg0[3], plg1[3])
  // then up to 3 direct-load steps (one-time tail, natural waits)
  for (int td = t + 4; td < len; ++td) {
    float q0 = lgbase[(size_t)td * NUM + j0];
    float q1 = lgbase[(size_t)td * NUM + off1];
    STEP_BODY(q0, q1)
  }
#undef STEP_BODY

  // ---- alpha_len[j] = (Kint - klast)*ln2 + log(w_len[j])
  const float LN2 = 0.6931471805599453f;
  float SigmaPrev = (float)(Kint - klast) * LN2;
  float alpha0 = SigmaPrev + __logf(w0_out);   // -inf for dead states: ok
  float alpha1 = SigmaPrev + __logf(w1_out);

  float v0 = alpha0 + trans[(LBL - 1) * LBL + j0];
  float v1 = alpha1 + trans[(LBL - 1) * LBL + j1];
  float M = wave_max64(fmaxf(v0, v1));
  float p = __expf(v0 - M) + __expf(v1 - M);
  #pragma unroll
  for (int o = 1; o < 64; o <<= 1) p += __shfl_xor(p, o);
  if (l == 0) out[b] = gold - (M + __logf(p));
}

extern "C" void kernel_launch(void* const* d_in, const int* in_sizes, int n_in,
                              void* d_out, int out_size, void* d_ws, size_t ws_size,
                              hipStream_t stream) {
  const float* logits = (const float*)d_in[0];
  const int*   labels = (const int*)d_in[1];
  const int*   lens   = (const int*)d_in[2];
  const float* trans  = (const float*)d_in[3];
  float* out = (float*)d_out;
  (void)in_sizes; (void)n_in; (void)out_size; (void)d_ws; (void)ws_size;
  crf_fwd<<<256, 64, 0, stream>>>(logits, labels, lens, trans, out);
}

// Round 8
// 581.614 us; speedup vs baseline: 2.0290x; 1.0355x over previous
//
#include <hip/hip_runtime.h>

// CRF forward, latency-optimized: ONE WAVE per sequence, no barriers, no
// fences, nothing but the raw dependence chain in the time loop.
// 256 blocks x 64 threads; lane l owns states j0=l, j1=l+64.
// E=exp(trans) in 128 VGPRs (f16). Multiplicative recurrence with a STALE
// power-of-2 normalizer (feedback form, no random walk):
//   w_t = (E·a_{t-1})*eL_t            (dots in f32 via v_dot2_f32_f16)
//   a_t = w_t * 2^-P_t                (P_t computed LAST step -> off-chain)
//   P_{t+1} = exponent(max w_t) - P_t + 6   (max tree runs in the shadow)
//   Kacc += P_t  (exact integer side chain; alpha = ln(w)+Kacc*ln2)
// Critical chain per step: ds_write -> (in-order LDS) ds_read(16xb128,
// broadcast) -> 128 dot2 -> *eL -> *sc -> cvt -> ds_write.  No waitcnt
// drains: in-loop global prefetch is unconditional (rows clamped to TB-1).

typedef _Float16 half_t;
typedef _Float16 h2 __attribute__((ext_vector_type(2)));
typedef _Float16 h8 __attribute__((ext_vector_type(8)));

#define TB  1024
#define NUM 126
#define LBL 128

__device__ __forceinline__ float dot2(h2 a, h2 b, float c) {
  return __builtin_amdgcn_fdot2(a, b, c, false);
}

template <int U>
__device__ __forceinline__ float dotu(h8 a, h8 e, float c) {
  return dot2(__builtin_shufflevector(a, a, 2 * U, 2 * U + 1),
              __builtin_shufflevector(e, e, 2 * U, 2 * U + 1), c);
}

template <int CTRL>
__device__ __forceinline__ float dpp_max_step(float x) {
  int xi = __float_as_int(x);
  int yi = __builtin_amdgcn_update_dpp(xi, xi, CTRL, 0xF, 0xF, false);
  return fmaxf(x, __int_as_float(yi));
}

// max over all 64 lanes -> uniform (SGPR) via readlane(63)
__device__ __forceinline__ float wave_max64(float x) {
  x = dpp_max_step<0x111>(x);  // row_shr:1
  x = dpp_max_step<0x112>(x);  // row_shr:2
  x = dpp_max_step<0x114>(x);  // row_shr:4
  x = dpp_max_step<0x118>(x);  // row_shr:8
  x = dpp_max_step<0x142>(x);  // row_bcast:15
  x = dpp_max_step<0x143>(x);  // row_bcast:31
  return __int_as_float(__builtin_amdgcn_readlane(__float_as_int(x), 63));
}

__global__ __launch_bounds__(64, 1)
void crf_fwd(const float* __restrict__ logits, const int* __restrict__ labels,
             const int* __restrict__ lens, const float* __restrict__ trans,
             float* __restrict__ out)
{
  const int b  = blockIdx.x;
  const int l  = threadIdx.x;      // lane 0..63
  const int j0 = l;                // state j0 (< 126: always a real label)
  const int j1 = l + 64;           // state j1 (126,127 on lanes 62,63)
  const int off1 = (j1 < NUM) ? j1 : (NUM - 1);  // clamped col (load safety)
  const float mask1 = (j1 < NUM) ? 1.0f : 0.0f;  // value mask for eL1
  const int len = lens[b];

  __shared__ h2 a_sh[64];          // dword l = (a[l], a[l+64]), f16
  h8* a_sh8 = (h8*)a_sh;

  const float* lgbase = logits + (size_t)b * TB * NUM;
  const int*   lab    = labels + (size_t)b * TB;

  // ---- E rows (f16) in registers, permuted to the a_sh interleaved order:
  // f16 position p in a_sh holds state i(p) = (p>>1) + 64*(p&1)
  h8 E0[16], E1[16];
  {
    const float* tr0 = trans + j0 * LBL;
    const float* tr1 = trans + j1 * LBL;
    #pragma unroll
    for (int q = 0; q < 16; ++q) {
      h8 v0, v1;
      #pragma unroll
      for (int e = 0; e < 8; ++e) {
        int p = 8 * q + e;
        int i = (p >> 1) + 64 * (p & 1);
        v0[e] = (half_t)__expf(tr0[i]);
        v1[e] = (half_t)__expf(tr1[i]);
      }
      E0[q] = v0; E1[q] = v1;
    }
  }

  // ---- gold score (one-time, off the recurrence)
  float g = 0.f;
  #pragma unroll
  for (int kk = 0; kk < 16; ++kk) {
    int t = l + 64 * kk;
    if (t < len) {
      int lt = lab[t];
      int lp = (t == 0) ? (LBL - 2) : lab[t - 1];   // start state = 126
      g += lgbase[(size_t)t * NUM + lt] + trans[lt * LBL + lp];
    }
  }
  if (l == 0) g += trans[(LBL - 1) * LBL + lab[len - 1]];  // -> end
  #pragma unroll
  for (int o = 1; o < 64; o <<= 1) g += __shfl_xor(g, o);
  const float gold = g;

  // ---- a_0 = one-hot(start=126); same-wave in-order DS
  {
    h2 a_init;
    a_init[0] = (half_t)0.0f;
    a_init[1] = (half_t)((j1 == LBL - 2) ? 1.0f : 0.0f);
    a_sh[l] = a_init;
  }

  // ---- logit prefetch: rows 0..3 unconditional (buffer is full TB rows)
  float plg0[4], plg1[4];
  #pragma unroll
  for (int d = 0; d < 4; ++d) {
    plg0[d] = lgbase[(size_t)d * NUM + j0];
    plg1[d] = lgbase[(size_t)d * NUM + off1];
  }

  int   P    = 6;                  // stale scale exponent (applied this step)
  int   Kacc = 0;                  // sum of applied exponents (a = w*2^-Kacc)
  int   Kout = 0;                  // Kacc at entry of last executed step
  float w0_out = 1.f, w1_out = 1.f;

#define STEP_BODY(Q0, Q1)                                                   \
  {                                                                         \
    float eL0 = __expf(Q0);                                                 \
    float eL1 = __expf(Q1) * mask1;                                         \
    float s0a = 0.f, s0b = 0.f, s1a = 0.f, s1b = 0.f;                       \
    _Pragma("unroll")                                                       \
    for (int q = 0; q < 16; q += 2) {                                       \
      h8 avA = a_sh8[q], avB = a_sh8[q + 1];  /* uniform addr broadcast */  \
      h8 e0A = E0[q], e0B = E0[q + 1], e1A = E1[q], e1B = E1[q + 1];        \
      s0a = dotu<0>(avA, e0A, s0a);  s0b = dotu<0>(avB, e0B, s0b);          \
      s1a = dotu<0>(avA, e1A, s1a);  s1b = dotu<0>(avB, e1B, s1b);          \
      s0a = dotu<1>(avA, e0A, s0a);  s0b = dotu<1>(avB, e0B, s0b);          \
      s1a = dotu<1>(avA, e1A, s1a);  s1b = dotu<1>(avB, e1B, s1b);          \
      s0a = dotu<2>(avA, e0A, s0a);  s0b = dotu<2>(avB, e0B, s0b);          \
      s1a = dotu<2>(avA, e1A, s1a);  s1b = dotu<2>(avB, e1B, s1b);          \
      s0a = dotu<3>(avA, e0A, s0a);  s0b = dotu<3>(avB, e0B, s0b);          \
      s1a = dotu<3>(avA, e1A, s1a);  s1b = dotu<3>(avB, e1B, s1b);          \
    }                                                                       \
    float w0 = (s0a + s0b) * eL0;                                           \
    float w1 = (s1a + s1b) * eL1;                                           \
    float sc = __int_as_float((127 - P) << 23);   /* 2^-P, SGPR, EXACT */   \
    h2 pk;                                                                  \
    pk[0] = (half_t)(w0 * sc);                                              \
    pk[1] = (half_t)(w1 * sc);                                              \
    a_sh[l] = pk;                    /* chain tail: mul,mul,cvt,write */    \
    Kout = Kacc;  Kacc += P;         /* SALU side chain */                  \
    /* shadow (next step's scale): runs in next step's LDS-latency window */\
    float m  = wave_max64(fmaxf(w0, w1));                                   \
    int   Em = ((__float_as_int(m) >> 23) & 0xFF) - 127;                    \
    P = Em - P + 6;                  /* feedback: bounded, no random walk */ \
    w0_out = w0; w1_out = w1;                                               \
  }

  int t = 0;
  // main loop: all in-loop prefetch loads unconditional (rows clamped)
  for (; t + 4 <= len; t += 4) {
    int r0 = t + 4, r1 = t + 5, r2 = t + 6, r3 = t + 7;
    r0 = (r0 < TB) ? r0 : (TB - 1);  r1 = (r1 < TB) ? r1 : (TB - 1);
    r2 = (r2 < TB) ? r2 : (TB - 1);  r3 = (r3 < TB) ? r3 : (TB - 1);
    STEP_BODY(plg0[0], plg1[0])
    plg0[0] = lgbase[(size_t)r0 * NUM + j0];
    plg1[0] = lgbase[(size_t)r0 * NUM + off1];
    STEP_BODY(plg0[1], plg1[1])
    plg0[1] = lgbase[(size_t)r1 * NUM + j0];
    plg1[1] = lgbase[(size_t)r1 * NUM + off1];
    STEP_BODY(plg0[2], plg1[2])
    plg0[2] = lgbase[(size_t)r2 * NUM + j0];
    plg1[2] = lgbase[(size_t)r2 * NUM + off1];
    STEP_BODY(plg0[3], plg1[3])
    plg0[3] = lgbase[(size_t)r3 * NUM + j0];
    plg1[3] = lgbase[(size_t)r3 * NUM + off1];
  }
  // remainder (slots already hold rows t..t+3)
  const int rem = len - t;
  if (rem > 0) STEP_BODY(plg0[0], plg1[0])
  if (rem > 1) STEP_BODY(plg0[1], plg1[1])
  if (rem > 2) STEP_BODY(plg0[2], plg1[2])
#undef STEP_BODY

  // ---- alpha_len[j] = Kout*ln2 + log(w_len[j]); norm = logsumexp(+trans_end)
  const float LN2 = 0.6931471805599453f;
  float SigmaPrev = (float)Kout * LN2;
  float alpha0 = SigmaPrev + __logf(w0_out);   // -inf for dead states: ok
  float alpha1 = SigmaPrev + __logf(w1_out);

  float v0 = alpha0 + trans[(LBL - 1) * LBL + j0];
  float v1 = alpha1 + trans[(LBL - 1) * LBL + j1];
  float M = wave_max64(fmaxf(v0, v1));
  float p = __expf(v0 - M) + __expf(v1 - M);
  #pragma unroll
  for (int o = 1; o < 64; o <<= 1) p += __shfl_xor(p, o);
  if (l == 0) out[b] = gold - (M + __logf(p));
}

extern "C" void kernel_launch(void* const* d_in, const int* in_sizes, int n_in,
                              void* d_out, int out_size, void* d_ws, size_t ws_size,
                              hipStream_t stream) {
  const float* logits = (const float*)d_in[0];
  const int*   labels = (const int*)d_in[1];
  const int*   lens   = (const int*)d_in[2];
  const float* trans  = (const float*)d_in[3];
  float* out = (float*)d_out;
  (void)in_sizes; (void)n_in; (void)out_size; (void)d_ws; (void)ws_size;
  crf_fwd<<<256, 64, 0, stream>>>(logits, labels, lens, trans, out);
}